// Round 2
// baseline (2379.221 us; speedup 1.0000x reference)
//
#include <hip/hip_runtime.h>
#include <hip/hip_cooperative_groups.h>

namespace cg = cooperative_groups;

// ---------------------------------------------------------------------------
// Decoder: h0/c0 init GEMMs -> persistent cooperative LSTM (32 steps, W_hh in
// LDS, c in registers) -> one big FC GEMM. GEMMs: 128x128 LDS-staged bf16 MFMA.
// Sizes: B=64 T=32 E=512 H=1024 V=10000 F=2048.
// ---------------------------------------------------------------------------

#define B_  64
#define T_  32
#define E_  512
#define H_  1024
#define V_  10000
#define F_  2048

typedef short short8 __attribute__((ext_vector_type(8)));
typedef float floatx4 __attribute__((ext_vector_type(4)));

__device__ __forceinline__ float bf2f(unsigned short u) {
  union { unsigned int i; float f; } c; c.i = ((unsigned int)u) << 16; return c.f;
}
__device__ __forceinline__ unsigned short f2bf(float f) {
  union { float f; unsigned int i; } c; c.f = f;
  unsigned int x = c.i;
  return (unsigned short)((x + 0x7fffu + ((x >> 16) & 1u)) >> 16);
}
__device__ __forceinline__ float sigmoidf_(float x) {
  return 1.0f / (1.0f + __expf(-x));
}
// async global->LDS, 16B per lane. LDS dest must be wave-uniform base + lane*16.
__device__ __forceinline__ void gl_lds16(const unsigned short* g, unsigned short* l) {
  __builtin_amdgcn_global_load_lds(
      (const __attribute__((address_space(1))) unsigned int*)g,
      (__attribute__((address_space(3))) unsigned int*)l, 16, 0, 0);
}

// ---------------- fp32 -> bf16 bulk convert (vectorized, grid-stride) ------
__global__ __launch_bounds__(256) void cvt_f32_bf16(
    const float* __restrict__ src, unsigned short* __restrict__ dst, int n4) {
  int i = blockIdx.x * blockDim.x + threadIdx.x;
  int stride = gridDim.x * blockDim.x;
  for (; i < n4; i += stride) {
    float4 v = ((const float4*)src)[i];
    ushort4 o;
    o.x = f2bf(v.x); o.y = f2bf(v.y); o.z = f2bf(v.z); o.w = f2bf(v.w);
    ((ushort4*)dst)[i] = o;
  }
}

// ---------------- embedding gather -> bf16, rows ordered (t*64+b) ----------
__global__ __launch_bounds__(128) void embed_gather(
    const float* __restrict__ table, const int* __restrict__ captions,
    unsigned short* __restrict__ out) {
  int row = blockIdx.x;            // row = t*B + b
  int t = row >> 6, b = row & 63;
  int idx = captions[b * T_ + t];
  const float4* src = (const float4*)(table + (size_t)idx * E_);
  ushort4* dst = (ushort4*)(out + (size_t)row * E_);
  for (int e = threadIdx.x; e < E_ / 4; e += blockDim.x) {
    float4 v = src[e];
    ushort4 o;
    o.x = f2bf(v.x); o.y = f2bf(v.y); o.z = f2bf(v.z); o.w = f2bf(v.w);
    dst[e] = o;
  }
}

// ---------------- 128x128 LDS-staged bf16 MFMA GEMM ------------------------
// C = act(A @ W^T + b1 + b2).  A: [M,K] bf16 row-major, W: [N,K] bf16 row-major.
// K % 32 == 0. M/N tails handled by row-clamping loads + masking stores.
// Block 256 thr = 4 waves (2x2); wave tile 64x64 (16 accs); BK=32.
template <int ACT_SIGMOID, int OUT_BF16>
__global__ __launch_bounds__(256) void mfma_gemm128(
    const unsigned short* __restrict__ A, const unsigned short* __restrict__ W,
    const float* __restrict__ bias1, const float* __restrict__ bias2,
    void* __restrict__ out, int M, int N, int K) {
  __shared__ unsigned short At[128 * 32];   // [row][32] bf16, 8 KB
  __shared__ unsigned short Wt[128 * 32];   // 8 KB

  const int tid  = threadIdx.x;
  const int lane = tid & 63;
  const int wave = tid >> 6;
  const int l15  = lane & 15;
  const int quad = lane >> 4;
  const int kb   = quad * 8;
  const int wm   = (wave >> 1) * 64;
  const int wn   = (wave & 1) * 64;
  const int m0   = blockIdx.x * 128;
  const int n0   = blockIdx.y * 128;

  // staging: 512 16B-chunks per tile; chunk c: row=c>>2, koff=(c&3)*8
  const int c0i = tid, c1i = tid + 256;
  const int ar0 = c0i >> 2, ak0 = (c0i & 3) * 8;
  const int ar1 = c1i >> 2, ak1 = (c1i & 3) * 8;
  int am0 = m0 + ar0; if (am0 > M - 1) am0 = M - 1;
  int am1 = m0 + ar1; if (am1 > M - 1) am1 = M - 1;
  int wn0 = n0 + ar0; if (wn0 > N - 1) wn0 = N - 1;
  int wn1 = n0 + ar1; if (wn1 > N - 1) wn1 = N - 1;
  const unsigned short* Ag0 = A + (size_t)am0 * K + ak0;
  const unsigned short* Ag1 = A + (size_t)am1 * K + ak1;
  const unsigned short* Wg0 = W + (size_t)wn0 * K + ak0;
  const unsigned short* Wg1 = W + (size_t)wn1 * K + ak1;

  floatx4 acc[4][4];
#pragma unroll
  for (int i = 0; i < 4; ++i)
#pragma unroll
    for (int j = 0; j < 4; ++j) acc[i][j] = (floatx4){0.f, 0.f, 0.f, 0.f};

  for (int k0 = 0; k0 < K; k0 += 32) {
    gl_lds16(Ag0 + k0, &At[c0i * 8]);
    gl_lds16(Ag1 + k0, &At[c1i * 8]);
    gl_lds16(Wg0 + k0, &Wt[c0i * 8]);
    gl_lds16(Wg1 + k0, &Wt[c1i * 8]);
    __syncthreads();

    short8 a[4], b[4];
#pragma unroll
    for (int mt = 0; mt < 4; ++mt)
      a[mt] = *(const short8*)&At[(wm + mt * 16 + l15) * 32 + kb];
#pragma unroll
    for (int nt = 0; nt < 4; ++nt)
      b[nt] = *(const short8*)&Wt[(wn + nt * 16 + l15) * 32 + kb];
#pragma unroll
    for (int mt = 0; mt < 4; ++mt)
#pragma unroll
      for (int nt = 0; nt < 4; ++nt)
        acc[mt][nt] = __builtin_amdgcn_mfma_f32_16x16x32_bf16(a[mt], b[nt], acc[mt][nt], 0, 0, 0);
    __syncthreads();
  }

#pragma unroll
  for (int nt = 0; nt < 4; ++nt) {
    int col = n0 + wn + nt * 16 + l15;
    if (col >= N) continue;
    float bsum = (bias1 ? bias1[col] : 0.f) + (bias2 ? bias2[col] : 0.f);
#pragma unroll
    for (int mt = 0; mt < 4; ++mt) {
#pragma unroll
      for (int r = 0; r < 4; ++r) {
        int m = m0 + wm + mt * 16 + quad * 4 + r;
        if (m >= M) continue;
        float v = acc[mt][nt][r] + bsum;
        if (ACT_SIGMOID) v = sigmoidf_(v);
        if (OUT_BF16)
          ((unsigned short*)out)[(size_t)m * N + col] = f2bf(v);
        else
          ((float*)out)[(size_t)m * N + col] = v;
      }
    }
  }
}

// ---------------- persistent cooperative LSTM ------------------------------
// 256 blocks x 256 threads. Block b owns h-columns [4b, 4b+4) for all 4 gates:
// 16 W_hh rows (g*H + col), staged ONCE into LDS (padded rows: no bank
// conflicts), reused across all 32 steps. c state: 1 fp32 register/thread.
// Per step: gates[64B x 16n] via MFMA (4 waves, 4 indep acc chains over K),
// LDS round-trip, cell math, write h slice, grid-wide sync.
#define WSPAD 1032   // 1024 + 8 bf16 pad per row
__global__ __launch_bounds__(256, 1) void lstm_persistent(
    const unsigned short* __restrict__ W_hh_b,  // [4H,H] bf16
    const unsigned short* __restrict__ gx,      // [T,B,4H] bf16 (x-part+biases)
    const float* __restrict__ c0,               // [B,H] fp32
    unsigned short* __restrict__ h_all) {       // [(T+1),B,H] bf16, slot0=h0
  __shared__ unsigned short Ws[16 * WSPAD];     // ~33 KB
  __shared__ float gbuf[B_][17];                // padded, ~4.4 KB

  const int tid  = threadIdx.x;
  const int lane = tid & 63;
  const int wave = tid >> 6;        // m-tile: batches wave*16..+15
  const int l15  = lane & 15;
  const int quad = lane >> 4;
  const int kb   = quad * 8;
  const int colbase = blockIdx.x * 4;

  // ---- stage this block's 16 W_hh rows into LDS (once) ----
  // LDS row n <-> W_hh row (n>>2)*H + colbase + (n&3)   (gate-major)
  for (int c = tid; c < 16 * 128; c += 256) {         // 16B chunks
    int row = c >> 7, off = (c & 127) * 8;
    int grow = (row >> 2) * H_ + colbase + (row & 3);
    *(short8*)&Ws[row * WSPAD + off] =
        *(const short8*)(W_hh_b + (size_t)grow * H_ + off);
  }

  // ---- per-thread cell state ----
  const int cb  = tid >> 2;          // batch 0..63
  const int cj  = tid & 3;           // col-within-block 0..3
  const int col = colbase + cj;
  float c_reg = c0[cb * H_ + col];

  cg::grid_group grid = cg::this_grid();
  __syncthreads();

  for (int t = 0; t < T_; ++t) {
    const unsigned short* hp =
        h_all + (size_t)t * B_ * H_ + (size_t)(wave * 16 + l15) * H_ + kb;

    floatx4 a0 = (floatx4){0,0,0,0}, a1 = a0, a2 = a0, a3 = a0;
#pragma unroll
    for (int ks = 0; ks < 8; ++ks) {
      const int kk = ks * 128;
      short8 x0 = *(const short8*)(hp + kk);
      short8 x1 = *(const short8*)(hp + kk + 32);
      short8 x2 = *(const short8*)(hp + kk + 64);
      short8 x3 = *(const short8*)(hp + kk + 96);
      short8 w0 = *(const short8*)&Ws[l15 * WSPAD + kb + kk];
      short8 w1 = *(const short8*)&Ws[l15 * WSPAD + kb + kk + 32];
      short8 w2 = *(const short8*)&Ws[l15 * WSPAD + kb + kk + 64];
      short8 w3 = *(const short8*)&Ws[l15 * WSPAD + kb + kk + 96];
      a0 = __builtin_amdgcn_mfma_f32_16x16x32_bf16(x0, w0, a0, 0, 0, 0);
      a1 = __builtin_amdgcn_mfma_f32_16x16x32_bf16(x1, w1, a1, 0, 0, 0);
      a2 = __builtin_amdgcn_mfma_f32_16x16x32_bf16(x2, w2, a2, 0, 0, 0);
      a3 = __builtin_amdgcn_mfma_f32_16x16x32_bf16(x3, w3, a3, 0, 0, 0);
    }
    floatx4 acc = (a0 + a1) + (a2 + a3);

#pragma unroll
    for (int r = 0; r < 4; ++r)
      gbuf[wave * 16 + quad * 4 + r][l15] = acc[r];
    __syncthreads();

    // ---- cell math: thread owns (batch cb, col) ----
    const unsigned short* gxp = gx + ((size_t)t * B_ + cb) * (4 * H_) + col;
    float gi = gbuf[cb][0 + cj]  + bf2f(gxp[0 * H_]);
    float gf = gbuf[cb][4 + cj]  + bf2f(gxp[1 * H_]);
    float gg = gbuf[cb][8 + cj]  + bf2f(gxp[2 * H_]);
    float go = gbuf[cb][12 + cj] + bf2f(gxp[3 * H_]);
    gi = sigmoidf_(gi);
    gf = sigmoidf_(gf);
    gg = tanhf(gg);
    go = sigmoidf_(go);
    c_reg = gf * c_reg + gi * gg;
    float h = go * tanhf(c_reg);
    h_all[(size_t)(t + 1) * B_ * H_ + cb * H_ + col] = f2bf(h);

    __threadfence();   // make h visible device-wide before the barrier
    grid.sync();
  }
}

// ---------------------------------------------------------------------------
extern "C" void kernel_launch(void* const* d_in, const int* in_sizes, int n_in,
                              void* d_out, int out_size, void* d_ws, size_t ws_size,
                              hipStream_t stream) {
  const float* features    = (const float*)d_in[0];
  const int*   captions    = (const int*)d_in[1];
  const float* embed_table = (const float*)d_in[2];
  const float* W_init_h    = (const float*)d_in[3];
  const float* b_init_h    = (const float*)d_in[4];
  const float* W_init_c    = (const float*)d_in[5];
  const float* b_init_c    = (const float*)d_in[6];
  const float* W_ih        = (const float*)d_in[7];
  const float* b_ih        = (const float*)d_in[8];
  const float* W_hh        = (const float*)d_in[9];
  const float* b_hh        = (const float*)d_in[10];
  const float* W_fc        = (const float*)d_in[11];
  const float* b_fc        = (const float*)d_in[12];
  float* out = (float*)d_out;

  // ---- workspace carve-up (bump allocator, 256B aligned) ----
  char* ws = (char*)d_ws;
  auto alloc = [&](size_t bytes) -> char* {
    char* p = ws;
    ws += (bytes + 255) & ~(size_t)255;
    return p;
  };
  unsigned short* W_ih_b  = (unsigned short*)alloc((size_t)4 * H_ * E_ * 2);
  unsigned short* W_hh_b  = (unsigned short*)alloc((size_t)4 * H_ * H_ * 2);
  unsigned short* W_fc_b  = (unsigned short*)alloc((size_t)V_ * H_ * 2);
  unsigned short* Wih0_b  = (unsigned short*)alloc((size_t)H_ * F_ * 2);
  unsigned short* Wic0_b  = (unsigned short*)alloc((size_t)H_ * F_ * 2);
  unsigned short* feat_b  = (unsigned short*)alloc((size_t)B_ * F_ * 2);
  unsigned short* emb_b   = (unsigned short*)alloc((size_t)T_ * B_ * E_ * 2);
  unsigned short* gx_b    = (unsigned short*)alloc((size_t)T_ * B_ * 4 * H_ * 2);
  unsigned short* h_all   = (unsigned short*)alloc((size_t)(T_ + 1) * B_ * H_ * 2);
  float*          c_f32   = (float*)alloc((size_t)B_ * H_ * 4);
  (void)ws_size; (void)in_sizes; (void)n_in; (void)out_size;

  // ---- weight / input conversions to bf16 ----
  auto cvt = [&](const float* s, unsigned short* d, size_t n) {
    int n4 = (int)(n / 4);
    int blocks = (n4 + 255) / 256;
    if (blocks > 2048) blocks = 2048;
    hipLaunchKernelGGL(cvt_f32_bf16, dim3(blocks), dim3(256), 0, stream, s, d, n4);
  };
  cvt(W_ih, W_ih_b, (size_t)4 * H_ * E_);
  cvt(W_hh, W_hh_b, (size_t)4 * H_ * H_);
  cvt(W_fc, W_fc_b, (size_t)V_ * H_);
  cvt(W_init_h, Wih0_b, (size_t)H_ * F_);
  cvt(W_init_c, Wic0_b, (size_t)H_ * F_);
  cvt(features, feat_b, (size_t)B_ * F_);

  hipLaunchKernelGGL(embed_gather, dim3(T_ * B_), dim3(128), 0, stream,
                     embed_table, captions, emb_b);

  // ---- h0 (bf16 into h_all slot 0) and c0 (fp32) ----
  hipLaunchKernelGGL((mfma_gemm128<0, 1>), dim3(1, H_ / 128), dim3(256), 0, stream,
                     feat_b, Wih0_b, b_init_h, (const float*)nullptr,
                     (void*)h_all, B_, H_, F_);
  hipLaunchKernelGGL((mfma_gemm128<0, 0>), dim3(1, H_ / 128), dim3(256), 0, stream,
                     feat_b, Wic0_b, b_init_c, (const float*)nullptr,
                     (void*)c_f32, B_, H_, F_);

  // ---- gx = emb @ W_ih^T + b_ih + b_hh for all t ----
  hipLaunchKernelGGL((mfma_gemm128<0, 1>), dim3(T_ * B_ / 128, 4 * H_ / 128), dim3(256), 0, stream,
                     emb_b, W_ih_b, b_ih, b_hh, (void*)gx_b,
                     T_ * B_, 4 * H_, E_);

  // ---- persistent recurrent kernel (cooperative: grid-wide sync) ----
  {
    void* args[] = {(void*)&W_hh_b, (void*)&gx_b, (void*)&c_f32, (void*)&h_all};
    hipLaunchCooperativeKernel((void*)lstm_persistent, dim3(H_ / 4), dim3(256),
                               args, 0, stream);
  }

  // ---- final FC: out = sigmoid(h_all[1..32] @ W_fc^T + b_fc) ----
  hipLaunchKernelGGL((mfma_gemm128<1, 0>), dim3(T_ * B_ / 128, (V_ + 127) / 128), dim3(256), 0, stream,
                     h_all + (size_t)B_ * H_, W_fc_b, b_fc, (const float*)nullptr,
                     (void*)out, T_ * B_, V_, H_);
}

// Round 3
// 628.121 us; speedup vs baseline: 3.7878x; 3.7878x over previous
//
#include <hip/hip_runtime.h>

// ---------------------------------------------------------------------------
// Decoder: h0/c0 init GEMMs -> 32 per-step LSTM kernels (256 blocks each,
// W_hh slice in LDS) -> one big FC GEMM. GEMMs: 128x128 LDS-staged bf16 MFMA.
// Sizes: B=64 T=32 E=512 H=1024 V=10000 F=2048.
// Round-2 lesson: cooperative grid.sync costs ~60us/step on 8 XCDs (L2
// flush per sync) -- per-step launches are strictly better here.
// ---------------------------------------------------------------------------

#define B_  64
#define T_  32
#define E_  512
#define H_  1024
#define V_  10000
#define F_  2048

typedef short short8 __attribute__((ext_vector_type(8)));
typedef float floatx4 __attribute__((ext_vector_type(4)));

__device__ __forceinline__ float bf2f(unsigned short u) {
  union { unsigned int i; float f; } c; c.i = ((unsigned int)u) << 16; return c.f;
}
__device__ __forceinline__ unsigned short f2bf(float f) {
  union { float f; unsigned int i; } c; c.f = f;
  unsigned int x = c.i;
  return (unsigned short)((x + 0x7fffu + ((x >> 16) & 1u)) >> 16);
}
__device__ __forceinline__ float sigmoidf_(float x) {
  return 1.0f / (1.0f + __expf(-x));
}
// async global->LDS, 16B per lane. LDS dest must be wave-uniform base + lane*16.
__device__ __forceinline__ void gl_lds16(const unsigned short* g, unsigned short* l) {
  __builtin_amdgcn_global_load_lds(
      (const __attribute__((address_space(1))) unsigned int*)g,
      (__attribute__((address_space(3))) unsigned int*)l, 16, 0, 0);
}

// ---------------- fp32 -> bf16 bulk convert (vectorized, grid-stride) ------
__global__ __launch_bounds__(256) void cvt_f32_bf16(
    const float* __restrict__ src, unsigned short* __restrict__ dst, int n4) {
  int i = blockIdx.x * blockDim.x + threadIdx.x;
  int stride = gridDim.x * blockDim.x;
  for (; i < n4; i += stride) {
    float4 v = ((const float4*)src)[i];
    ushort4 o;
    o.x = f2bf(v.x); o.y = f2bf(v.y); o.z = f2bf(v.z); o.w = f2bf(v.w);
    ((ushort4*)dst)[i] = o;
  }
}

// ---------------- embedding gather -> bf16, rows ordered (t*64+b) ----------
__global__ __launch_bounds__(128) void embed_gather(
    const float* __restrict__ table, const int* __restrict__ captions,
    unsigned short* __restrict__ out) {
  int row = blockIdx.x;            // row = t*B + b
  int t = row >> 6, b = row & 63;
  int idx = captions[b * T_ + t];
  const float4* src = (const float4*)(table + (size_t)idx * E_);
  ushort4* dst = (ushort4*)(out + (size_t)row * E_);
  for (int e = threadIdx.x; e < E_ / 4; e += blockDim.x) {
    float4 v = src[e];
    ushort4 o;
    o.x = f2bf(v.x); o.y = f2bf(v.y); o.z = f2bf(v.z); o.w = f2bf(v.w);
    dst[e] = o;
  }
}

// ---------------- 128x128 LDS-staged bf16 MFMA GEMM ------------------------
// C = act(A @ W^T + b1 + b2).  A: [M,K] bf16 row-major, W: [N,K] bf16 row-major.
// K % 32 == 0. M/N tails handled by row-clamping loads + masking stores.
// Block 256 thr = 4 waves (2x2); wave tile 64x64 (16 accs); BK=32.
template <int ACT_SIGMOID, int OUT_BF16>
__global__ __launch_bounds__(256) void mfma_gemm128(
    const unsigned short* __restrict__ A, const unsigned short* __restrict__ W,
    const float* __restrict__ bias1, const float* __restrict__ bias2,
    void* __restrict__ out, int M, int N, int K) {
  __shared__ unsigned short At[128 * 32];   // [row][32] bf16, 8 KB
  __shared__ unsigned short Wt[128 * 32];   // 8 KB

  const int tid  = threadIdx.x;
  const int lane = tid & 63;
  const int wave = tid >> 6;
  const int l15  = lane & 15;
  const int quad = lane >> 4;
  const int kb   = quad * 8;
  const int wm   = (wave >> 1) * 64;
  const int wn   = (wave & 1) * 64;
  const int m0   = blockIdx.x * 128;
  const int n0   = blockIdx.y * 128;

  // staging: 512 16B-chunks per tile; chunk c: row=c>>2, koff=(c&3)*8
  const int c0i = tid, c1i = tid + 256;
  const int ar0 = c0i >> 2, ak0 = (c0i & 3) * 8;
  const int ar1 = c1i >> 2, ak1 = (c1i & 3) * 8;
  int am0 = m0 + ar0; if (am0 > M - 1) am0 = M - 1;
  int am1 = m0 + ar1; if (am1 > M - 1) am1 = M - 1;
  int wn0 = n0 + ar0; if (wn0 > N - 1) wn0 = N - 1;
  int wn1 = n0 + ar1; if (wn1 > N - 1) wn1 = N - 1;
  const unsigned short* Ag0 = A + (size_t)am0 * K + ak0;
  const unsigned short* Ag1 = A + (size_t)am1 * K + ak1;
  const unsigned short* Wg0 = W + (size_t)wn0 * K + ak0;
  const unsigned short* Wg1 = W + (size_t)wn1 * K + ak1;

  floatx4 acc[4][4];
#pragma unroll
  for (int i = 0; i < 4; ++i)
#pragma unroll
    for (int j = 0; j < 4; ++j) acc[i][j] = (floatx4){0.f, 0.f, 0.f, 0.f};

  for (int k0 = 0; k0 < K; k0 += 32) {
    gl_lds16(Ag0 + k0, &At[c0i * 8]);
    gl_lds16(Ag1 + k0, &At[c1i * 8]);
    gl_lds16(Wg0 + k0, &Wt[c0i * 8]);
    gl_lds16(Wg1 + k0, &Wt[c1i * 8]);
    __syncthreads();

    short8 a[4], b[4];
#pragma unroll
    for (int mt = 0; mt < 4; ++mt)
      a[mt] = *(const short8*)&At[(wm + mt * 16 + l15) * 32 + kb];
#pragma unroll
    for (int nt = 0; nt < 4; ++nt)
      b[nt] = *(const short8*)&Wt[(wn + nt * 16 + l15) * 32 + kb];
#pragma unroll
    for (int mt = 0; mt < 4; ++mt)
#pragma unroll
      for (int nt = 0; nt < 4; ++nt)
        acc[mt][nt] = __builtin_amdgcn_mfma_f32_16x16x32_bf16(a[mt], b[nt], acc[mt][nt], 0, 0, 0);
    __syncthreads();
  }

#pragma unroll
  for (int nt = 0; nt < 4; ++nt) {
    int col = n0 + wn + nt * 16 + l15;
    if (col >= N) continue;
    float bsum = (bias1 ? bias1[col] : 0.f) + (bias2 ? bias2[col] : 0.f);
#pragma unroll
    for (int mt = 0; mt < 4; ++mt) {
#pragma unroll
      for (int r = 0; r < 4; ++r) {
        int m = m0 + wm + mt * 16 + quad * 4 + r;
        if (m >= M) continue;
        float v = acc[mt][nt][r] + bsum;
        if (ACT_SIGMOID) v = sigmoidf_(v);
        if (OUT_BF16)
          ((unsigned short*)out)[(size_t)m * N + col] = f2bf(v);
        else
          ((float*)out)[(size_t)m * N + col] = v;
      }
    }
  }
}

// ---------------- per-step LSTM kernel -------------------------------------
// Grid 256 blocks x 256 thr. Block b owns h-cols [4b,4b+4) for all 4 gates:
// 16 W_hh rows (gate-major), staged to LDS from L2 each launch (32 KB).
// Wave w computes batches [16w,16w+16) x those 16 gate-rows via MFMA
// (4 independent acc chains over K=1024). Cell math via LDS round-trip.
#define WSPAD 1032   // 1024 + 8 bf16 pad per row
__global__ __launch_bounds__(256, 1) void lstm_step(
    const unsigned short* __restrict__ W_hh_b,  // [4H,H] bf16
    const unsigned short* __restrict__ gx_t,    // [B,4H] bf16 (x-part+biases)
    float* __restrict__ c,                      // [B,H] f32, in-place
    const unsigned short* __restrict__ h_in,    // [B,H] bf16
    unsigned short* __restrict__ h_out) {       // [B,H] bf16
  __shared__ unsigned short Ws[16 * WSPAD];     // ~33 KB
  __shared__ float gbuf[B_][17];                // padded, ~4.4 KB

  const int tid  = threadIdx.x;
  const int lane = tid & 63;
  const int wave = tid >> 6;        // m-tile: batches wave*16..+15
  const int l15  = lane & 15;
  const int quad = lane >> 4;
  const int kb   = quad * 8;
  const int colbase = blockIdx.x * 4;

  // ---- stage this block's 16 W_hh rows into LDS ----
  // LDS row n <-> W_hh row (n>>2)*H + colbase + (n&3)   (gate-major)
#pragma unroll
  for (int it = 0; it < 8; ++it) {
    int cc = tid + it * 256;                    // 16B chunk index
    int row = cc >> 7, off = (cc & 127) * 8;
    int grow = (row >> 2) * H_ + colbase + (row & 3);
    *(short8*)&Ws[row * WSPAD + off] =
        *(const short8*)(W_hh_b + (size_t)grow * H_ + off);
  }
  __syncthreads();

  const unsigned short* hp = h_in + (size_t)(wave * 16 + l15) * H_ + kb;

  floatx4 a0 = (floatx4){0,0,0,0}, a1 = a0, a2 = a0, a3 = a0;
#pragma unroll
  for (int ks = 0; ks < 8; ++ks) {
    const int kk = ks * 128;
    short8 x0 = *(const short8*)(hp + kk);
    short8 x1 = *(const short8*)(hp + kk + 32);
    short8 x2 = *(const short8*)(hp + kk + 64);
    short8 x3 = *(const short8*)(hp + kk + 96);
    short8 w0 = *(const short8*)&Ws[l15 * WSPAD + kb + kk];
    short8 w1 = *(const short8*)&Ws[l15 * WSPAD + kb + kk + 32];
    short8 w2 = *(const short8*)&Ws[l15 * WSPAD + kb + kk + 64];
    short8 w3 = *(const short8*)&Ws[l15 * WSPAD + kb + kk + 96];
    a0 = __builtin_amdgcn_mfma_f32_16x16x32_bf16(x0, w0, a0, 0, 0, 0);
    a1 = __builtin_amdgcn_mfma_f32_16x16x32_bf16(x1, w1, a1, 0, 0, 0);
    a2 = __builtin_amdgcn_mfma_f32_16x16x32_bf16(x2, w2, a2, 0, 0, 0);
    a3 = __builtin_amdgcn_mfma_f32_16x16x32_bf16(x3, w3, a3, 0, 0, 0);
  }
  floatx4 acc = (a0 + a1) + (a2 + a3);

#pragma unroll
  for (int r = 0; r < 4; ++r)
    gbuf[wave * 16 + quad * 4 + r][l15] = acc[r];
  __syncthreads();

  // ---- cell math: thread owns (batch cb, col colbase+cj) ----
  const int cb  = tid >> 2;          // batch 0..63
  const int cj  = tid & 3;           // col-within-block 0..3
  const int col = colbase + cj;
  const unsigned short* gxp = gx_t + (size_t)cb * (4 * H_) + col;
  float gi = gbuf[cb][0 + cj]  + bf2f(gxp[0 * H_]);
  float gf = gbuf[cb][4 + cj]  + bf2f(gxp[1 * H_]);
  float gg = gbuf[cb][8 + cj]  + bf2f(gxp[2 * H_]);
  float go = gbuf[cb][12 + cj] + bf2f(gxp[3 * H_]);
  gi = sigmoidf_(gi);
  gf = sigmoidf_(gf);
  gg = tanhf(gg);
  go = sigmoidf_(go);
  int ci = cb * H_ + col;
  float cn = gf * c[ci] + gi * gg;
  c[ci] = cn;
  h_out[ci] = f2bf(go * tanhf(cn));
}

// ---------------------------------------------------------------------------
extern "C" void kernel_launch(void* const* d_in, const int* in_sizes, int n_in,
                              void* d_out, int out_size, void* d_ws, size_t ws_size,
                              hipStream_t stream) {
  const float* features    = (const float*)d_in[0];
  const int*   captions    = (const int*)d_in[1];
  const float* embed_table = (const float*)d_in[2];
  const float* W_init_h    = (const float*)d_in[3];
  const float* b_init_h    = (const float*)d_in[4];
  const float* W_init_c    = (const float*)d_in[5];
  const float* b_init_c    = (const float*)d_in[6];
  const float* W_ih        = (const float*)d_in[7];
  const float* b_ih        = (const float*)d_in[8];
  const float* W_hh        = (const float*)d_in[9];
  const float* b_hh        = (const float*)d_in[10];
  const float* W_fc        = (const float*)d_in[11];
  const float* b_fc        = (const float*)d_in[12];
  float* out = (float*)d_out;

  // ---- workspace carve-up (bump allocator, 256B aligned) ----
  char* ws = (char*)d_ws;
  auto alloc = [&](size_t bytes) -> char* {
    char* p = ws;
    ws += (bytes + 255) & ~(size_t)255;
    return p;
  };
  unsigned short* W_ih_b  = (unsigned short*)alloc((size_t)4 * H_ * E_ * 2);
  unsigned short* W_hh_b  = (unsigned short*)alloc((size_t)4 * H_ * H_ * 2);
  unsigned short* W_fc_b  = (unsigned short*)alloc((size_t)V_ * H_ * 2);
  unsigned short* Wih0_b  = (unsigned short*)alloc((size_t)H_ * F_ * 2);
  unsigned short* Wic0_b  = (unsigned short*)alloc((size_t)H_ * F_ * 2);
  unsigned short* feat_b  = (unsigned short*)alloc((size_t)B_ * F_ * 2);
  unsigned short* emb_b   = (unsigned short*)alloc((size_t)T_ * B_ * E_ * 2);
  unsigned short* gx_b    = (unsigned short*)alloc((size_t)T_ * B_ * 4 * H_ * 2);
  unsigned short* h_all   = (unsigned short*)alloc((size_t)(T_ + 1) * B_ * H_ * 2);
  float*          c_f32   = (float*)alloc((size_t)B_ * H_ * 4);
  (void)ws_size; (void)in_sizes; (void)n_in; (void)out_size;

  // ---- weight / input conversions to bf16 ----
  auto cvt = [&](const float* s, unsigned short* d, size_t n) {
    int n4 = (int)(n / 4);
    int blocks = (n4 + 255) / 256;
    if (blocks > 2048) blocks = 2048;
    hipLaunchKernelGGL(cvt_f32_bf16, dim3(blocks), dim3(256), 0, stream, s, d, n4);
  };
  cvt(W_ih, W_ih_b, (size_t)4 * H_ * E_);
  cvt(W_hh, W_hh_b, (size_t)4 * H_ * H_);
  cvt(W_fc, W_fc_b, (size_t)V_ * H_);
  cvt(W_init_h, Wih0_b, (size_t)H_ * F_);
  cvt(W_init_c, Wic0_b, (size_t)H_ * F_);
  cvt(features, feat_b, (size_t)B_ * F_);

  hipLaunchKernelGGL(embed_gather, dim3(T_ * B_), dim3(128), 0, stream,
                     embed_table, captions, emb_b);

  // ---- h0 (bf16 into h_all slot 0) and c0 (fp32) ----
  hipLaunchKernelGGL((mfma_gemm128<0, 1>), dim3(1, H_ / 128), dim3(256), 0, stream,
                     feat_b, Wih0_b, b_init_h, (const float*)nullptr,
                     (void*)h_all, B_, H_, F_);
  hipLaunchKernelGGL((mfma_gemm128<0, 0>), dim3(1, H_ / 128), dim3(256), 0, stream,
                     feat_b, Wic0_b, b_init_c, (const float*)nullptr,
                     (void*)c_f32, B_, H_, F_);

  // ---- gx = emb @ W_ih^T + b_ih + b_hh for all t ----
  hipLaunchKernelGGL((mfma_gemm128<0, 1>), dim3(T_ * B_ / 128, 4 * H_ / 128), dim3(256), 0, stream,
                     emb_b, W_ih_b, b_ih, b_hh, (void*)gx_b,
                     T_ * B_, 4 * H_, E_);

  // ---- 32 sequential recurrent steps (256 blocks each: 1 block/CU) ----
  for (int t = 0; t < T_; ++t) {
    hipLaunchKernelGGL(lstm_step, dim3(H_ / 4), dim3(256), 0, stream,
                       W_hh_b,
                       gx_b + (size_t)t * B_ * 4 * H_,
                       c_f32,
                       h_all + (size_t)t * B_ * H_,
                       h_all + (size_t)(t + 1) * B_ * H_);
  }

  // ---- final FC: out = sigmoid(h_all[1..32] @ W_fc^T + b_fc) ----
  hipLaunchKernelGGL((mfma_gemm128<1, 0>), dim3(T_ * B_ / 128, (V_ + 127) / 128), dim3(256), 0, stream,
                     h_all + (size_t)B_ * H_, W_fc_b, b_fc, (const float*)nullptr,
                     (void*)out, T_ * B_, V_, H_);
}

// Round 4
// 619.842 us; speedup vs baseline: 3.8384x; 1.0134x over previous
//
#include <hip/hip_runtime.h>

// ---------------------------------------------------------------------------
// Decoder: fused cvt -> h0/c0 init GEMMs -> 32 per-step LSTM kernels
// (512 thr, K-split waves, async W_hh->LDS) -> one big FC GEMM.
// GEMMs: 128x128 LDS-staged bf16 MFMA with XOR bank swizzle.
// Round-2 lesson: cooperative grid.sync ~60us/step (8-XCD flush) -- per-step
// launches win. Round-3 lesson: step kernel was 1 wave/SIMD (no TLP) and
// GEMM LDS reads were 8-way bank-conflicted.
// ---------------------------------------------------------------------------

#define B_  64
#define T_  32
#define E_  512
#define H_  1024
#define V_  10000
#define F_  2048

typedef short short8 __attribute__((ext_vector_type(8)));
typedef float floatx4 __attribute__((ext_vector_type(4)));

__device__ __forceinline__ float bf2f(unsigned short u) {
  union { unsigned int i; float f; } c; c.i = ((unsigned int)u) << 16; return c.f;
}
__device__ __forceinline__ unsigned short f2bf(float f) {
  union { float f; unsigned int i; } c; c.f = f;
  unsigned int x = c.i;
  return (unsigned short)((x + 0x7fffu + ((x >> 16) & 1u)) >> 16);
}
__device__ __forceinline__ float sigmoidf_(float x) {
  return 1.0f / (1.0f + __expf(-x));
}
// async global->LDS, 16B per lane. LDS dest = wave-uniform base + lane*16.
__device__ __forceinline__ void gl_lds16(const unsigned short* g, unsigned short* l) {
  __builtin_amdgcn_global_load_lds(
      (const __attribute__((address_space(1))) unsigned int*)g,
      (__attribute__((address_space(3))) unsigned int*)l, 16, 0, 0);
}

// ---------------- fused fp32 -> bf16 convert for all 6 arrays --------------
// chunk counts (float4 units)
#define C_WIH  524288    // 4H*E/4
#define C_WHH  1048576   // 4H*H/4
#define C_WFC  2560000   // V*H/4
#define C_WI0  524288    // H*F/4
#define C_WC0  524288
#define C_FEA  32768     // B*F/4
#define C_TOT  (C_WIH + C_WHH + C_WFC + C_WI0 + C_WC0 + C_FEA)

__global__ __launch_bounds__(256) void cvt_all(
    const float* __restrict__ s0, const float* __restrict__ s1,
    const float* __restrict__ s2, const float* __restrict__ s3,
    const float* __restrict__ s4, const float* __restrict__ s5,
    unsigned short* __restrict__ d0, unsigned short* __restrict__ d1,
    unsigned short* __restrict__ d2, unsigned short* __restrict__ d3,
    unsigned short* __restrict__ d4, unsigned short* __restrict__ d5) {
  int i = blockIdx.x * blockDim.x + threadIdx.x;
  int stride = gridDim.x * blockDim.x;
  for (; i < C_TOT; i += stride) {
    const float* s; unsigned short* d; int j = i;
    if (j < C_WIH)            { s = s0; d = d0; }
    else if ((j -= C_WIH) < C_WHH) { s = s1; d = d1; }
    else if ((j -= C_WHH) < C_WFC) { s = s2; d = d2; }
    else if ((j -= C_WFC) < C_WI0) { s = s3; d = d3; }
    else if ((j -= C_WI0) < C_WC0) { s = s4; d = d4; }
    else { j -= C_WC0; s = s5; d = d5; }
    float4 v = ((const float4*)s)[j];
    ushort4 o;
    o.x = f2bf(v.x); o.y = f2bf(v.y); o.z = f2bf(v.z); o.w = f2bf(v.w);
    ((ushort4*)d)[j] = o;
  }
}

// ---------------- embedding gather -> bf16, rows ordered (t*64+b) ----------
__global__ __launch_bounds__(128) void embed_gather(
    const float* __restrict__ table, const int* __restrict__ captions,
    unsigned short* __restrict__ out) {
  int row = blockIdx.x;            // row = t*B + b
  int t = row >> 6, b = row & 63;
  int idx = captions[b * T_ + t];
  const float4* src = (const float4*)(table + (size_t)idx * E_);
  ushort4* dst = (ushort4*)(out + (size_t)row * E_);
  for (int e = threadIdx.x; e < E_ / 4; e += blockDim.x) {
    float4 v = src[e];
    ushort4 o;
    o.x = f2bf(v.x); o.y = f2bf(v.y); o.z = f2bf(v.z); o.w = f2bf(v.w);
    dst[e] = o;
  }
}

// ---------------- 128x128 LDS-staged bf16 MFMA GEMM (XOR bank swizzle) -----
// C = act(A @ W^T + b1 + b2).  A: [M,K] bf16 row-major, W: [N,K] bf16 row-major.
// LDS rows of 32 shorts, 16B chunk slot s holds global chunk s^(row&3):
// global side permuted (per-lane scatter ok), LDS side stays contiguous for
// global_load_lds; fragment reads then span all 32 banks (2-way = free).
template <int ACT_SIGMOID, int OUT_BF16>
__global__ __launch_bounds__(256) void mfma_gemm128(
    const unsigned short* __restrict__ A, const unsigned short* __restrict__ W,
    const float* __restrict__ bias1, const float* __restrict__ bias2,
    void* __restrict__ out, int M, int N, int K) {
  __shared__ unsigned short At[128 * 32];   // 8 KB
  __shared__ unsigned short Wt[128 * 32];   // 8 KB

  const int tid  = threadIdx.x;
  const int lane = tid & 63;
  const int wave = tid >> 6;
  const int l15  = lane & 15;
  const int quad = lane >> 4;
  const int wm   = (wave >> 1) * 64;
  const int wn   = (wave & 1) * 64;
  const int m0   = blockIdx.x * 128;
  const int n0   = blockIdx.y * 128;
  const int ksl  = (quad ^ (l15 & 3)) * 8;  // swizzled k-chunk for fragment reads

  // staging: 512 16B-chunks per tile; chunk c: row=c>>2, slot=c&3,
  // global k-chunk = slot ^ (row&3)
  const int c0i = tid, c1i = tid + 256;
  const int ar0 = c0i >> 2, ak0 = (((c0i & 3) ^ (ar0 & 3)) * 8);
  const int ar1 = c1i >> 2, ak1 = (((c1i & 3) ^ (ar1 & 3)) * 8);
  int am0 = m0 + ar0; if (am0 > M - 1) am0 = M - 1;
  int am1 = m0 + ar1; if (am1 > M - 1) am1 = M - 1;
  int wn0 = n0 + ar0; if (wn0 > N - 1) wn0 = N - 1;
  int wn1 = n0 + ar1; if (wn1 > N - 1) wn1 = N - 1;
  const unsigned short* Ag0 = A + (size_t)am0 * K + ak0;
  const unsigned short* Ag1 = A + (size_t)am1 * K + ak1;
  const unsigned short* Wg0 = W + (size_t)wn0 * K + ak0;
  const unsigned short* Wg1 = W + (size_t)wn1 * K + ak1;

  floatx4 acc[4][4];
#pragma unroll
  for (int i = 0; i < 4; ++i)
#pragma unroll
    for (int j = 0; j < 4; ++j) acc[i][j] = (floatx4){0.f, 0.f, 0.f, 0.f};

  for (int k0 = 0; k0 < K; k0 += 32) {
    gl_lds16(Ag0 + k0, &At[c0i * 8]);
    gl_lds16(Ag1 + k0, &At[c1i * 8]);
    gl_lds16(Wg0 + k0, &Wt[c0i * 8]);
    gl_lds16(Wg1 + k0, &Wt[c1i * 8]);
    __syncthreads();

    short8 a[4], b[4];
#pragma unroll
    for (int mt = 0; mt < 4; ++mt)
      a[mt] = *(const short8*)&At[(wm + mt * 16 + l15) * 32 + ksl];
#pragma unroll
    for (int nt = 0; nt < 4; ++nt)
      b[nt] = *(const short8*)&Wt[(wn + nt * 16 + l15) * 32 + ksl];
#pragma unroll
    for (int mt = 0; mt < 4; ++mt)
#pragma unroll
      for (int nt = 0; nt < 4; ++nt)
        acc[mt][nt] = __builtin_amdgcn_mfma_f32_16x16x32_bf16(a[mt], b[nt], acc[mt][nt], 0, 0, 0);
    __syncthreads();
  }

#pragma unroll
  for (int nt = 0; nt < 4; ++nt) {
    int col = n0 + wn + nt * 16 + l15;
    if (col >= N) continue;
    float bsum = (bias1 ? bias1[col] : 0.f) + (bias2 ? bias2[col] : 0.f);
#pragma unroll
    for (int mt = 0; mt < 4; ++mt) {
#pragma unroll
      for (int r = 0; r < 4; ++r) {
        int m = m0 + wm + mt * 16 + quad * 4 + r;
        if (m >= M) continue;
        float v = acc[mt][nt][r] + bsum;
        if (ACT_SIGMOID) v = sigmoidf_(v);
        if (OUT_BF16)
          ((unsigned short*)out)[(size_t)m * N + col] = f2bf(v);
        else
          ((float*)out)[(size_t)m * N + col] = v;
      }
    }
  }
}

// ---------------- per-step LSTM kernel (512 thr, K-split) ------------------
// Grid 256 blocks. Block b owns h-cols [4b,4b+4) x 4 gates = 16 W_hh rows
// (32 KB, async-staged to LDS each launch). Wave w: batch-tile w&3,
// K-half w>>2; 16 MFMAs in 4 chains. Partial sums reduced through LDS.
// h prefetched to regs before the staging barrier (latency overlap).
#define WSPAD 1032   // 1024 + 8 bf16 pad per row (stride 516 dwords: 2-way)
__global__ __launch_bounds__(512, 2) void lstm_step(
    const unsigned short* __restrict__ W_hh_b,  // [4H,H] bf16
    const unsigned short* __restrict__ gx_t,    // [B,4H] bf16 (x-part+biases)
    float* __restrict__ c,                      // [B,H] f32, in-place
    const unsigned short* __restrict__ h_in,    // [B,H] bf16
    unsigned short* __restrict__ h_out) {       // [B,H] bf16
  __shared__ unsigned short Ws[16 * WSPAD];     // ~33 KB
  __shared__ float gbuf[2][B_][17];             // ~8.7 KB

  const int tid  = threadIdx.x;
  const int lane = tid & 63;
  const int wave = tid >> 6;        // 0..7
  const int l15  = lane & 15;
  const int quad = lane >> 4;
  const int kb   = quad * 8;
  const int kh   = wave >> 2;       // K half: [kh*512, kh*512+512)
  const int mt   = wave & 3;        // batch tile: batches mt*16..+15
  const int colbase = blockIdx.x * 4;

  // ---- async-stage 16 W_hh rows into LDS (gate-major: row n <-> W_hh row
  // (n>>2)*H + colbase + (n&3)); each wave writes contiguous 1KB half-rows --
#pragma unroll
  for (int it = 0; it < 4; ++it) {
    int row  = it * 4 + (wave >> 1);
    int half = wave & 1;
    int grow = (row >> 2) * H_ + colbase + (row & 3);
    gl_lds16(W_hh_b + (size_t)grow * H_ + half * 512 + lane * 8,
             &Ws[row * WSPAD + half * 512]);
  }

  // ---- prefetch h fragment (16 x 16B) into registers (overlaps staging) ---
  const unsigned short* hp = h_in + (size_t)(mt * 16 + l15) * H_ + kh * 512 + kb;
  short8 hx[16];
#pragma unroll
  for (int i = 0; i < 16; ++i)
    hx[i] = *(const short8*)(hp + i * 32);

  // ---- prefetch cell inputs (waves 0-3 only; wave-uniform branch) ---------
  const int cb = tid >> 2, cj = tid & 3;
  float gxi = 0.f, gxf = 0.f, gxg = 0.f, gxo = 0.f, c_old = 0.f;
  if (tid < 256) {
    const unsigned short* gxp = gx_t + (size_t)cb * (4 * H_) + colbase + cj;
    gxi = bf2f(gxp[0 * H_]);
    gxf = bf2f(gxp[1 * H_]);
    gxg = bf2f(gxp[2 * H_]);
    gxo = bf2f(gxp[3 * H_]);
    c_old = c[cb * H_ + colbase + cj];
  }

  __syncthreads();   // drains vmcnt: staging + prefetches complete

  floatx4 a0 = (floatx4){0,0,0,0}, a1 = a0, a2 = a0, a3 = a0;
#pragma unroll
  for (int i = 0; i < 16; i += 4) {
    short8 w0 = *(const short8*)&Ws[l15 * WSPAD + kh * 512 + kb + (i + 0) * 32];
    short8 w1 = *(const short8*)&Ws[l15 * WSPAD + kh * 512 + kb + (i + 1) * 32];
    short8 w2 = *(const short8*)&Ws[l15 * WSPAD + kh * 512 + kb + (i + 2) * 32];
    short8 w3 = *(const short8*)&Ws[l15 * WSPAD + kh * 512 + kb + (i + 3) * 32];
    a0 = __builtin_amdgcn_mfma_f32_16x16x32_bf16(hx[i + 0], w0, a0, 0, 0, 0);
    a1 = __builtin_amdgcn_mfma_f32_16x16x32_bf16(hx[i + 1], w1, a1, 0, 0, 0);
    a2 = __builtin_amdgcn_mfma_f32_16x16x32_bf16(hx[i + 2], w2, a2, 0, 0, 0);
    a3 = __builtin_amdgcn_mfma_f32_16x16x32_bf16(hx[i + 3], w3, a3, 0, 0, 0);
  }
  floatx4 acc = (a0 + a1) + (a2 + a3);

#pragma unroll
  for (int r = 0; r < 4; ++r)
    gbuf[kh][mt * 16 + quad * 4 + r][l15] = acc[r];
  __syncthreads();

  // ---- cell math: thread owns (batch cb, col colbase+cj); waves 0-3 -------
  if (tid < 256) {
    float gi = gbuf[0][cb][0  + cj] + gbuf[1][cb][0  + cj] + gxi;
    float gf = gbuf[0][cb][4  + cj] + gbuf[1][cb][4  + cj] + gxf;
    float gg = gbuf[0][cb][8  + cj] + gbuf[1][cb][8  + cj] + gxg;
    float go = gbuf[0][cb][12 + cj] + gbuf[1][cb][12 + cj] + gxo;
    gi = sigmoidf_(gi);
    gf = sigmoidf_(gf);
    gg = tanhf(gg);
    go = sigmoidf_(go);
    int ci = cb * H_ + colbase + cj;
    float cn = gf * c_old + gi * gg;
    c[ci] = cn;
    h_out[ci] = f2bf(go * tanhf(cn));
  }
}

// ---------------------------------------------------------------------------
extern "C" void kernel_launch(void* const* d_in, const int* in_sizes, int n_in,
                              void* d_out, int out_size, void* d_ws, size_t ws_size,
                              hipStream_t stream) {
  const float* features    = (const float*)d_in[0];
  const int*   captions    = (const int*)d_in[1];
  const float* embed_table = (const float*)d_in[2];
  const float* W_init_h    = (const float*)d_in[3];
  const float* b_init_h    = (const float*)d_in[4];
  const float* W_init_c    = (const float*)d_in[5];
  const float* b_init_c    = (const float*)d_in[6];
  const float* W_ih        = (const float*)d_in[7];
  const float* b_ih        = (const float*)d_in[8];
  const float* W_hh        = (const float*)d_in[9];
  const float* b_hh        = (const float*)d_in[10];
  const float* W_fc        = (const float*)d_in[11];
  const float* b_fc        = (const float*)d_in[12];
  float* out = (float*)d_out;

  // ---- workspace carve-up (bump allocator, 256B aligned) ----
  char* ws = (char*)d_ws;
  auto alloc = [&](size_t bytes) -> char* {
    char* p = ws;
    ws += (bytes + 255) & ~(size_t)255;
    return p;
  };
  unsigned short* W_ih_b  = (unsigned short*)alloc((size_t)4 * H_ * E_ * 2);
  unsigned short* W_hh_b  = (unsigned short*)alloc((size_t)4 * H_ * H_ * 2);
  unsigned short* W_fc_b  = (unsigned short*)alloc((size_t)V_ * H_ * 2);
  unsigned short* Wih0_b  = (unsigned short*)alloc((size_t)H_ * F_ * 2);
  unsigned short* Wic0_b  = (unsigned short*)alloc((size_t)H_ * F_ * 2);
  unsigned short* feat_b  = (unsigned short*)alloc((size_t)B_ * F_ * 2);
  unsigned short* emb_b   = (unsigned short*)alloc((size_t)T_ * B_ * E_ * 2);
  unsigned short* gx_b    = (unsigned short*)alloc((size_t)T_ * B_ * 4 * H_ * 2);
  unsigned short* h_all   = (unsigned short*)alloc((size_t)(T_ + 1) * B_ * H_ * 2);
  float*          c_f32   = (float*)alloc((size_t)B_ * H_ * 4);
  (void)ws_size; (void)in_sizes; (void)n_in; (void)out_size;

  // ---- one fused fp32->bf16 conversion for all weights/features ----
  hipLaunchKernelGGL(cvt_all, dim3(4096), dim3(256), 0, stream,
                     W_ih, W_hh, W_fc, W_init_h, W_init_c, features,
                     W_ih_b, W_hh_b, W_fc_b, Wih0_b, Wic0_b, feat_b);

  hipLaunchKernelGGL(embed_gather, dim3(T_ * B_), dim3(128), 0, stream,
                     embed_table, captions, emb_b);

  // ---- h0 (bf16 into h_all slot 0) and c0 (fp32) ----
  hipLaunchKernelGGL((mfma_gemm128<0, 1>), dim3(1, H_ / 128), dim3(256), 0, stream,
                     feat_b, Wih0_b, b_init_h, (const float*)nullptr,
                     (void*)h_all, B_, H_, F_);
  hipLaunchKernelGGL((mfma_gemm128<0, 0>), dim3(1, H_ / 128), dim3(256), 0, stream,
                     feat_b, Wic0_b, b_init_c, (const float*)nullptr,
                     (void*)c_f32, B_, H_, F_);

  // ---- gx = emb @ W_ih^T + b_ih + b_hh for all t ----
  hipLaunchKernelGGL((mfma_gemm128<0, 1>), dim3(T_ * B_ / 128, 4 * H_ / 128), dim3(256), 0, stream,
                     emb_b, W_ih_b, b_ih, b_hh, (void*)gx_b,
                     T_ * B_, 4 * H_, E_);

  // ---- 32 sequential recurrent steps (256 blocks x 512 thr) ----
  for (int t = 0; t < T_; ++t) {
    hipLaunchKernelGGL(lstm_step, dim3(H_ / 4), dim3(512), 0, stream,
                       W_hh_b,
                       gx_b + (size_t)t * B_ * 4 * H_,
                       c_f32,
                       h_all + (size_t)t * B_ * H_,
                       h_all + (size_t)(t + 1) * B_ * H_);
  }

  // ---- final FC: out = sigmoid(h_all[1..32] @ W_fc^T + b_fc) ----
  hipLaunchKernelGGL((mfma_gemm128<1, 0>), dim3(T_ * B_ / 128, (V_ + 127) / 128), dim3(256), 0, stream,
                     h_all + (size_t)B_ * H_, W_fc_b, b_fc, (const float*)nullptr,
                     (void*)out, T_ * B_, V_, H_);
}